// Round 6
// baseline (88.348 us; speedup 1.0000x reference)
//
#include <hip/hip_runtime.h>

#define N 1024
#define M 2048
#define P 20
#define THREADS 512   // 8 waves/block
#define WAVES 8
#define CHUNKS 64                 // gt chunks of 32 rows
#define GROUPS 16                 // pred groups of 64 rows
#define ROWS_PER_CHUNK (M / CHUNKS)            // 32
#define ROWS_PER_WAVE (ROWS_PER_CHUNK / WAVES) // 4

// out layout (float*): matched_points [0,40960) row n at n*40
//                      confidence     [40960,41984) at 40960+n
//                      indices(float) [41984,43008) at 41984+n
// ws layout: float ws_d[CHUNKS][N] ; int ws_i[CHUNKS][N]  (512 KB of 256 MB ws)

__global__ __launch_bounds__(THREADS, 8) void pm_partial(
    const float* __restrict__ pred, const float* __restrict__ gt,
    float* __restrict__ ws_d, int* __restrict__ ws_i)
{
    const int tid   = threadIdx.x;
    const int wave  = tid >> 6;
    const int lane  = tid & 63;
    const int chunk = blockIdx.x;   // gt rows [chunk*32, chunk*32+32)
    const int group = blockIdx.y;   // pred rows [group*64, group*64+64)

    // Stage this chunk's 32 gt rows (5 KB) into LDS, coalesced, shared by all 8 waves.
    __shared__ float s_gt[ROWS_PER_CHUNK * 40];
    {
        const float4* gsrc = (const float4*)(gt + chunk * ROWS_PER_CHUNK * 40);
        for (int t = tid; t < ROWS_PER_CHUNK * 10; t += THREADS)
            ((float4*)s_gt)[t] = gsrc[t];
    }

    // lane <-> pred row: load own row straight from global (one-time, overlaps staging).
    float pr[40];
    {
        const float4* pp = (const float4*)(pred + (group * 64 + lane) * 40);
#pragma unroll
        for (int j = 0; j < 10; ++j) {
            float4 v = pp[j];
            pr[4*j+0] = v.x; pr[4*j+1] = v.y; pr[4*j+2] = v.z; pr[4*j+3] = v.w;
        }
    }
    __syncthreads();

    // Each wave scans its 4 gt rows via LDS broadcast reads (wave-uniform addr).
    float bd = 3.4e38f;
    int   bi = 0x7fffffff;
#pragma unroll
    for (int r = 0; r < ROWS_PER_WAVE; ++r) {
        const int row = wave * ROWS_PER_WAVE + r;
        const float4* gp = (const float4*)(s_gt + row * 40);
        float acc = 0.0f;
        // Expression-identical to the bitwise-exact round-2 kernel (raw v_sqrt_f32
        // verified absmax 0.0 in round 5).
#pragma unroll
        for (int q = 0; q < 10; ++q) {
            float4 g = gp[q];
            float dx0 = pr[4*q+0] - g.x;
            float dy0 = pr[4*q+1] - g.y;
            float dx1 = pr[4*q+2] - g.z;
            float dy1 = pr[4*q+3] - g.w;
            acc += __builtin_amdgcn_sqrtf(dx0*dx0 + dy0*dy0);
            acc += __builtin_amdgcn_sqrtf(dx1*dx1 + dy1*dy1);
        }
        float dist = acc * (1.0f / P);
        if (dist < bd) { bd = dist; bi = chunk * ROWS_PER_CHUNK + row; } // ascending row
    }

    // Combine the block's 8 waves: ascending wave == ascending gt index, strict <
    // keeps the first occurrence.
    __shared__ float s_d[WAVES][64];
    __shared__ int   s_i[WAVES][64];
    s_d[wave][lane] = bd;
    s_i[wave][lane] = bi;
    __syncthreads();
    if (wave == 0) {
#pragma unroll
        for (int w = 1; w < WAVES; ++w) {
            float od = s_d[w][lane];
            int   oi = s_i[w][lane];
            if (od < bd) { bd = od; bi = oi; }
        }
        const int n = group * 64 + lane;
        ws_d[chunk * N + n] = bd;   // [chunk][row]: coalesced write & read
        ws_i[chunk * N + n] = bi;
    }
}

__global__ __launch_bounds__(256) void pm_final(
    const float* __restrict__ gt, const float* __restrict__ ws_d,
    const int* __restrict__ ws_i, float* __restrict__ out)
{
    const int tid = threadIdx.x;
    const int n   = blockIdx.x * 256 + tid;       // one pred row per thread

    float fd = ws_d[n];
    int   fi = ws_i[n];
    for (int c = 1; c < CHUNKS; ++c) {            // ascending chunk = ascending gt idx
        float od = ws_d[c * N + n];
        int   oi = ws_i[c * N + n];
        if (od < fd) { fd = od; fi = oi; }        // strict <: first occurrence
    }

    float conf = (fd > 2.0f) ? 0.0f : expf(-fd);
    out[40960 + n] = conf;
    out[41984 + n] = (float)fi;

    __shared__ int s_fi[256];
    s_fi[tid] = fi;
    __syncthreads();

    // Cooperative matched-row copy: 256 rows * 40 floats, coalesced.
    const int base_row = blockIdx.x * 256;
    for (int t = tid; t < 256 * 40; t += 256) {
        const int r = t / 40;
        const int e = t - r * 40;
        out[(base_row + r) * 40 + e] = gt[s_fi[r] * 40 + e];
    }
}

extern "C" void kernel_launch(void* const* d_in, const int* in_sizes, int n_in,
                              void* d_out, int out_size, void* d_ws, size_t ws_size,
                              hipStream_t stream) {
    const float* pred = (const float*)d_in[0];   // (1024, 20, 2) fp32
    const float* gt   = (const float*)d_in[1];   // (2048, 20, 2) fp32
    float* out  = (float*)d_out;                 // 43008 floats
    float* ws_d = (float*)d_ws;                  // CHUNKS*N floats
    int*   ws_i = (int*)((float*)d_ws + CHUNKS * N);
    (void)in_sizes; (void)n_in; (void)out_size; (void)ws_size;

    dim3 grid1(CHUNKS, GROUPS);
    pm_partial<<<grid1, THREADS, 0, stream>>>(pred, gt, ws_d, ws_i);
    pm_final<<<N / 256, 256, 0, stream>>>(gt, ws_d, ws_i, out);
}

// Round 7
// 73.715 us; speedup vs baseline: 1.1985x; 1.1985x over previous
//
#include <hip/hip_runtime.h>

#define N 1024
#define M 2048
#define P 20
#define THREADS 256   // 4 waves/block
#define WAVES 4
#define CHUNKS 128                // gt chunks of 16 rows
#define GROUPS 16                 // pred groups of 64 rows
#define RPC (M / CHUNKS)          // 16 gt rows per chunk
#define RPW (RPC / WAVES)         // 4 gt rows per wave

// out layout (float*): matched_points [0,40960) row n at n*40
//                      confidence     [40960,41984) at 40960+n
//                      indices(float) [41984,43008) at 41984+n
// ws layout: float ws_d[CHUNKS][N] ; int ws_i[CHUNKS][N]  (1 MB of 256 MB ws)

__global__ __launch_bounds__(THREADS) void pm_partial(
    const float* __restrict__ pred, const float* __restrict__ gt,
    float* __restrict__ ws_d, int* __restrict__ ws_i)
{
    const int tid   = threadIdx.x;
    const int wave  = tid >> 6;
    const int lane  = tid & 63;
    const int chunk = blockIdx.x;   // gt rows [chunk*16, chunk*16+16)
    const int group = blockIdx.y;   // pred rows [group*64, group*64+64)

    // Stage this chunk's 16 gt rows (2.5 KB) into LDS, coalesced.
    __shared__ float s_gt[RPC * 40];
    if (tid < RPC * 10)
        ((float4*)s_gt)[tid] = ((const float4*)(gt + chunk * RPC * 40))[tid];

    // lane <-> pred row: own row into registers (one-time global read).
    float pr[40];
    {
        const float4* pp = (const float4*)(pred + (group * 64 + lane) * 40);
#pragma unroll
        for (int j = 0; j < 10; ++j) {
            float4 v = pp[j];
            pr[4*j+0] = v.x; pr[4*j+1] = v.y; pr[4*j+2] = v.z; pr[4*j+3] = v.w;
        }
    }
    __syncthreads();

    // Each wave scans its 4 gt rows via LDS broadcast (wave-uniform address).
    // unroll 2 -> two independent acc chains in flight (sqrt+add chain is the
    // per-row latency floor), without 4x register blowup.
    float bd = 3.4e38f;
    int   bi = 0x7fffffff;
#pragma unroll 2
    for (int r = 0; r < RPW; ++r) {
        const int row = wave * RPW + r;
        const float4* gp = (const float4*)(s_gt + row * 40);
        float acc = 0.0f;
        // Expression-identical to the bitwise-exact round-2 form; raw v_sqrt_f32
        // verified absmax 0.0 in rounds 5-6.
#pragma unroll
        for (int q = 0; q < 10; ++q) {
            float4 g = gp[q];
            float dx0 = pr[4*q+0] - g.x;
            float dy0 = pr[4*q+1] - g.y;
            float dx1 = pr[4*q+2] - g.z;
            float dy1 = pr[4*q+3] - g.w;
            acc += __builtin_amdgcn_sqrtf(dx0*dx0 + dy0*dy0);
            acc += __builtin_amdgcn_sqrtf(dx1*dx1 + dy1*dy1);
        }
        float dist = acc * (1.0f / P);
        if (dist < bd) { bd = dist; bi = chunk * RPC + row; }  // ascending row
    }

    // Combine the block's 4 waves: ascending wave == ascending gt index,
    // strict < keeps the first occurrence.
    __shared__ float s_d[WAVES][64];
    __shared__ int   s_i[WAVES][64];
    s_d[wave][lane] = bd;
    s_i[wave][lane] = bi;
    __syncthreads();
    if (wave == 0) {
#pragma unroll
        for (int w = 1; w < WAVES; ++w) {
            float od = s_d[w][lane];
            int   oi = s_i[w][lane];
            if (od < bd) { bd = od; bi = oi; }
        }
        const int n = group * 64 + lane;
        ws_d[chunk * N + n] = bd;   // [chunk][row]: coalesced write
        ws_i[chunk * N + n] = bi;
    }
}

#define F_ROWS 32   // pred rows per pm_final block
#define F_SUB 8     // threads cooperating per pred row

__global__ __launch_bounds__(256) void pm_final(
    const float* __restrict__ gt, const float* __restrict__ ws_d,
    const int* __restrict__ ws_i, float* __restrict__ out)
{
    const int tid = threadIdx.x;
    const int row = tid >> 3;          // 0..31 within block
    const int sub = tid & (F_SUB - 1); // 0..7
    const int n   = blockIdx.x * F_ROWS + row;

    // Each of 8 threads scans 16 interleaved chunks: 16 independent loads in
    // flight per thread -> latency hidden by MLP, not wave count.
    float fd = 3.4e38f;
    int   fi = 0x7fffffff;
#pragma unroll
    for (int k = 0; k < CHUNKS / F_SUB; ++k) {
        const int c = sub + k * F_SUB;
        float od = ws_d[c * N + n];
        int   oi = ws_i[c * N + n];
        // chunk order interleaved -> MUST tie-break on index for first-occurrence
        if (od < fd || (od == fd && oi < fi)) { fd = od; fi = oi; }
    }

    __shared__ float s_d[F_ROWS][F_SUB];
    __shared__ int   s_i[F_ROWS][F_SUB];
    __shared__ int   s_fi[F_ROWS];
    s_d[row][sub] = fd;
    s_i[row][sub] = fi;
    __syncthreads();

    if (tid < F_ROWS) {               // one thread finishes each row
        float rd = s_d[tid][0];
        int   ri = s_i[tid][0];
#pragma unroll
        for (int s = 1; s < F_SUB; ++s) {
            float od = s_d[tid][s];
            int   oi = s_i[tid][s];
            if (od < rd || (od == rd && oi < ri)) { rd = od; ri = oi; }
        }
        const int nn = blockIdx.x * F_ROWS + tid;
        float conf = (rd > 2.0f) ? 0.0f : expf(-rd);
        out[40960 + nn] = conf;
        out[41984 + nn] = (float)ri;
        s_fi[tid] = ri;
    }
    __syncthreads();

    // Matched-row copy: 32 rows * 40 floats per block, coalesced writes.
    const int base_row = blockIdx.x * F_ROWS;
    for (int t = tid; t < F_ROWS * 40; t += 256) {
        const int r = t / 40;
        const int e = t - r * 40;
        out[(base_row + r) * 40 + e] = gt[s_fi[r] * 40 + e];
    }
}

extern "C" void kernel_launch(void* const* d_in, const int* in_sizes, int n_in,
                              void* d_out, int out_size, void* d_ws, size_t ws_size,
                              hipStream_t stream) {
    const float* pred = (const float*)d_in[0];   // (1024, 20, 2) fp32
    const float* gt   = (const float*)d_in[1];   // (2048, 20, 2) fp32
    float* out  = (float*)d_out;                 // 43008 floats
    float* ws_d = (float*)d_ws;                  // CHUNKS*N floats
    int*   ws_i = (int*)((float*)d_ws + CHUNKS * N);
    (void)in_sizes; (void)n_in; (void)out_size; (void)ws_size;

    dim3 grid1(CHUNKS, GROUPS);
    pm_partial<<<grid1, THREADS, 0, stream>>>(pred, gt, ws_d, ws_i);
    pm_final<<<N / F_ROWS, 256, 0, stream>>>(gt, ws_d, ws_i, out);
}